// Round 8
// baseline (740.499 us; speedup 1.0000x reference)
//
#include <hip/hip_runtime.h>
#include <hip/hip_bf16.h>
#include <hip/hip_fp16.h>
#include <stdint.h>

#define NF 64
#define NC 40
#define ZROW 64        // padded z row: 64 halves = 128 B = 2 full cache lines
#define SCAN_BLK 1024  // elements scanned per block (256 threads x 4)
#define MAXBKT 512     // bucket count cap (fits LDS histogram)

// ---------------------------------------------------------------------------
// Detect whether edge_index was uploaded as int32 or int64.
// ---------------------------------------------------------------------------
__global__ void detect_dtype_kernel(const unsigned int* __restrict__ p, int* __restrict__ flag,
                                    int n_check) {
    __shared__ int s_any;
    if (threadIdx.x == 0) s_any = 0;
    __syncthreads();
    int any = 0;
    for (int i = threadIdx.x; i < n_check; i += blockDim.x) {
        if (p[2 * i + 1] != 0u) any = 1;
    }
    if (any) atomicOr(&s_any, 1);
    __syncthreads();
    if (threadIdx.x == 0) *flag = s_any;
}

__device__ __forceinline__ long long load_idx(const void* p, long long i, int is32) {
    if (is32) return (long long)((const int*)p)[i];
    return ((const long long*)p)[i];
}

__global__ void zero2_kernel(int* __restrict__ cnt, int N, int* __restrict__ bcnt, int nb) {
    int i = blockIdx.x * blockDim.x + threadIdx.x;
    if (i < N) cnt[i] = 0;
    if (i < nb) bcnt[i] = 0;
}

// Per-destination count (atomic, cnt region is L2-resident) + LDS-aggregated
// bucket histogram. 2048 edges per block.
__global__ void count_bucket_kernel(const void* __restrict__ ei, int* __restrict__ cnt,
                                    int* __restrict__ bcnt, const int* __restrict__ flag,
                                    long long E, int shift) {
    __shared__ int h[MAXBKT];
    for (int i = threadIdx.x; i < MAXBKT; i += blockDim.x) h[i] = 0;
    __syncthreads();
    int is32 = *flag;
    long long base = (long long)blockIdx.x * 2048 + threadIdx.x;
#pragma unroll
    for (int j = 0; j < 8; ++j) {
        long long e = base + j * 256;
        if (e < E) {
            int c = (int)load_idx(ei, E + e, is32);
            atomicAdd(&cnt[c], 1);
            atomicAdd(&h[c >> shift], 1);
        }
    }
    __syncthreads();
    for (int i = threadIdx.x; i < MAXBKT; i += blockDim.x)
        if (h[i]) atomicAdd(&bcnt[i], h[i]);
}

// Exclusive scan of bucket counts (nb <= 512) -> bfill frontier counters
__global__ void bscan_kernel(const int* __restrict__ bcnt, int* __restrict__ bfill, int nb) {
    __shared__ int sd[MAXBKT];
    int t = threadIdx.x;
    int v = (t < nb) ? bcnt[t] : 0;
    sd[t] = v;
    __syncthreads();
#pragma unroll
    for (int off = 1; off < MAXBKT; off <<= 1) {
        int a = (t >= off) ? sd[t - off] : 0;
        __syncthreads();
        sd[t] += a;
        __syncthreads();
    }
    if (t < nb) bfill[t] = sd[t] - v;
}

// Per-block exclusive scan of cnt into row_ptr (block-local), block totals -> aux
__global__ void scanA_kernel(const int* __restrict__ cnt, int* __restrict__ row_ptr,
                             int* __restrict__ aux, int N) {
    __shared__ int sd[256];
    int t = threadIdx.x;
    int base = blockIdx.x * SCAN_BLK + t * 4;
    int v[4];
    int s = 0;
#pragma unroll
    for (int j = 0; j < 4; ++j) {
        v[j] = (base + j < N) ? cnt[base + j] : 0;
        s += v[j];
    }
    sd[t] = s;
    __syncthreads();
#pragma unroll
    for (int off = 1; off < 256; off <<= 1) {
        int a = (t >= off) ? sd[t - off] : 0;
        __syncthreads();
        sd[t] += a;
        __syncthreads();
    }
    int run = sd[t] - s;
#pragma unroll
    for (int j = 0; j < 4; ++j) {
        if (base + j < N) row_ptr[base + j] = run;
        run += v[j];
    }
    if (t == 255) aux[blockIdx.x] = sd[255];
}

__global__ void scanB_kernel(int* __restrict__ aux, int nb) {
    __shared__ int sd[128];
    int t = threadIdx.x;
    int v = (t < nb) ? aux[t] : 0;
    sd[t] = v;
    __syncthreads();
#pragma unroll
    for (int off = 1; off < 128; off <<= 1) {
        int a = (t >= off) ? sd[t - off] : 0;
        __syncthreads();
        sd[t] += a;
        __syncthreads();
    }
    if (t < nb) aux[t] = sd[t] - v;
}

// row_ptr[i] += aux[block(i)]; dinv[i] = rsqrt(1+cnt[i]); cnt[i] = 0 (-> fill ctr)
__global__ void scanC_kernel(int* __restrict__ row_ptr, const int* __restrict__ aux,
                             int* __restrict__ cnt, float* __restrict__ dinv, int N, int E) {
    int i = blockIdx.x * blockDim.x + threadIdx.x;
    if (i < N) {
        row_ptr[i] += aux[i >> 10];
        int c = cnt[i];
        dinv[i] = rsqrtf(1.0f + (float)c);
        cnt[i] = 0;
    }
    if (i == 0) row_ptr[N] = E;
}

// Partition edges into destination-range buckets. Bucket frontiers are
// sequential write streams -> full-line writes.
__global__ void partition_kernel(const void* __restrict__ ei, int* __restrict__ bfill,
                                 int2* __restrict__ ebuf, const int* __restrict__ flag,
                                 long long E, int shift) {
    long long e = (long long)blockIdx.x * blockDim.x + threadIdx.x;
    if (e >= E) return;
    int is32 = *flag;
    int r = (int)load_idx(ei, e, is32);
    int c = (int)load_idx(ei, E + e, is32);
    int pos = atomicAdd(&bfill[c >> shift], 1);
    ebuf[pos] = make_int2(r, c);
}

// Fill csr_src from bucket-ordered edges: each bucket's csr region (~14 KB)
// stays L2-resident -> partial-line RMWs merge before writeback.
__global__ void bucket_fill_kernel(const int2* __restrict__ ebuf, const int* __restrict__ row_ptr,
                                   int* __restrict__ fillc, int* __restrict__ csr_src,
                                   long long E) {
    long long e = (long long)blockIdx.x * blockDim.x + threadIdx.x;
    if (e >= E) return;
    int2 rc = ebuf[e];
    int pos = row_ptr[rc.y] + atomicAdd(&fillc[rc.y], 1);
    csr_src[pos] = rc.x;
}

// z[i][c] = half( dinv[i] * sum_f x[i][f] * W[c][f] ), rows padded to 64 halves.
// One wave per node; lane c owns class c; W row in VGPRs; x row via wave-uniform
// pointer (scalarizes); coalesced 128B row store. No LDS, no spill.
__global__ __launch_bounds__(256, 2)
void zgemm_kernel(const float* __restrict__ x, const float* __restrict__ W,
                  const float* __restrict__ dinv, __half* __restrict__ z, int N) {
    int lane = threadIdx.x & 63;
    int gwave = (blockIdx.x * blockDim.x + threadIdx.x) >> 6;
    int nwaves = (gridDim.x * blockDim.x) >> 6;

    int c = (lane < NC) ? lane : (NC - 1);
    float wreg[NF];
    const float4* wr = (const float4*)(W + (size_t)c * NF);
#pragma unroll
    for (int i = 0; i < NF / 4; ++i) {
        float4 wv = wr[i];
        wreg[4 * i + 0] = wv.x;
        wreg[4 * i + 1] = wv.y;
        wreg[4 * i + 2] = wv.z;
        wreg[4 * i + 3] = wv.w;
    }

    for (int node = gwave; node < N; node += nwaves) {
        int un = __builtin_amdgcn_readfirstlane(node);
        const float* xr = x + (size_t)un * NF;
        float a0 = 0.f, a1 = 0.f, a2 = 0.f, a3 = 0.f;
#pragma unroll
        for (int k = 0; k < NF; k += 4) {
            a0 += xr[k + 0] * wreg[k + 0];
            a1 += xr[k + 1] * wreg[k + 1];
            a2 += xr[k + 2] * wreg[k + 2];
            a3 += xr[k + 3] * wreg[k + 3];
        }
        float acc = (a0 + a1) + (a2 + a3);
        float di = dinv[un];
        float v = (lane < NC) ? di * acc : 0.0f;
        z[(size_t)un * ZROW + lane] = __float2half(v);
    }
}

// Two nodes per wave: half h = lane>>5 owns node wave*2+h; lane sub = lane&31
// holds half2 (classes 2*sub, 2*sub+1). Gathers move 4B/lane, one instruction
// covers both nodes' neighbor rows.
__global__ void hop_kernel(const __half* __restrict__ vin, __half* __restrict__ vout,
                           const int* __restrict__ row_ptr, const int* __restrict__ csr_src,
                           const float* __restrict__ dinv, int N) {
    int t = blockIdx.x * blockDim.x + threadIdx.x;
    int lane = threadIdx.x & 63;
    int half = lane >> 5;
    int sub = lane & 31;
    int node = ((t >> 6) << 1) + half;
    if (node >= N) return;

    int beg = row_ptr[node];
    int end = row_ptr[node + 1];
    int deg = end - beg;

    const unsigned int* v32 = (const unsigned int*)vin;
    unsigned int u = v32[(size_t)node * (ZROW / 2) + sub];
    float2 acc = __half22float2(*reinterpret_cast<const __half2*>(&u));

    int idx = (sub < deg) ? csr_src[beg + sub] : 0;
    int m = (deg < 32) ? deg : 32;
    for (int k = 0; k < m; ++k) {
        int s = __shfl(idx, k + (half << 5));
        unsigned int uu = v32[(size_t)s * (ZROW / 2) + sub];
        float2 v = __half22float2(*reinterpret_cast<const __half2*>(&uu));
        acc.x += v.x;
        acc.y += v.y;
    }
    for (int k = 32; k < deg; ++k) {  // rare (Poisson lambda=12.5)
        int s = csr_src[beg + k];
        unsigned int uu = v32[(size_t)s * (ZROW / 2) + sub];
        float2 v = __half22float2(*reinterpret_cast<const __half2*>(&uu));
        acc.x += v.x;
        acc.y += v.y;
    }

    float di = dinv[node];
    float d2 = di * di;
    __half2 o = __float22half2_rn(make_float2(d2 * acc.x, d2 * acc.y));
    ((unsigned int*)vout)[(size_t)node * (ZROW / 2) + sub] = *reinterpret_cast<unsigned int*>(&o);
}

// Final hop fused with bias + relu + log_softmax; same 2-node layout; reduction
// within each 32-lane half; direct contiguous float2 stores (160B per node).
__global__ void hop_final_kernel(const __half* __restrict__ vin, const float* __restrict__ b,
                                 float* __restrict__ out, const int* __restrict__ row_ptr,
                                 const int* __restrict__ csr_src, const float* __restrict__ dinv,
                                 int N) {
    int t = blockIdx.x * blockDim.x + threadIdx.x;
    int lane = threadIdx.x & 63;
    int half = lane >> 5;
    int sub = lane & 31;
    int node = ((t >> 6) << 1) + half;
    if (node >= N) return;

    int beg = row_ptr[node];
    int end = row_ptr[node + 1];
    int deg = end - beg;

    const unsigned int* v32 = (const unsigned int*)vin;
    unsigned int u = v32[(size_t)node * (ZROW / 2) + sub];
    float2 acc = __half22float2(*reinterpret_cast<const __half2*>(&u));

    int idx = (sub < deg) ? csr_src[beg + sub] : 0;
    int m = (deg < 32) ? deg : 32;
    for (int k = 0; k < m; ++k) {
        int s = __shfl(idx, k + (half << 5));
        unsigned int uu = v32[(size_t)s * (ZROW / 2) + sub];
        float2 v = __half22float2(*reinterpret_cast<const __half2*>(&uu));
        acc.x += v.x;
        acc.y += v.y;
    }
    for (int k = 32; k < deg; ++k) {
        int s = csr_src[beg + k];
        unsigned int uu = v32[(size_t)s * (ZROW / 2) + sub];
        float2 v = __half22float2(*reinterpret_cast<const __half2*>(&uu));
        acc.x += v.x;
        acc.y += v.y;
    }

    float di = dinv[node];
    float2 bv = (sub < NC / 2) ? ((const float2*)b)[sub] : make_float2(0.f, 0.f);
    float lx = fmaxf(di * acc.x + bv.x, 0.0f);  // pad lanes: acc=0,bv=0 -> 0
    float ly = fmaxf(di * acc.y + bv.y, 0.0f);

    float mx = fmaxf(lx, ly);
#pragma unroll
    for (int off = 16; off > 0; off >>= 1) mx = fmaxf(mx, __shfl_xor(mx, off));
    float e = (sub < NC / 2) ? (__expf(lx - mx) + __expf(ly - mx)) : 0.0f;
#pragma unroll
    for (int off = 16; off > 0; off >>= 1) e += __shfl_xor(e, off);
    float lse = mx + __logf(e);

    if (sub < NC / 2)
        ((float2*)out)[(size_t)node * (NC / 2) + sub] = make_float2(lx - lse, ly - lse);
}

extern "C" void kernel_launch(void* const* d_in, const int* in_sizes, int n_in,
                              void* d_out, int out_size, void* d_ws, size_t ws_size,
                              hipStream_t stream) {
    const float* x = (const float*)d_in[0];
    const void* ei = d_in[1];
    const float* W = (const float*)d_in[2];
    const float* b = (const float*)d_in[3];
    float* out = (float*)d_out;

    const int N = in_sizes[0] / NF;          // 100000
    const long long E = in_sizes[1] / 2;     // 1250000

    // bucket geometry: destinations per bucket = 1<<shift, NBK <= 512
    int shift = 8;
    while ((((N - 1) >> shift) + 1) > MAXBKT) ++shift;
    int NBK = ((N - 1) >> shift) + 1;        // 391 for N=100000

    // workspace layout (256B aligned chunks)
    size_t off = 0;
    int* flag = (int*)((char*)d_ws + off);
    off += 256;
    int* cnt = (int*)((char*)d_ws + off);           // later reused as fill counters
    off += ((size_t)N * 4 + 255) & ~(size_t)255;
    int* row_ptr = (int*)((char*)d_ws + off);
    off += ((size_t)(N + 1) * 4 + 255) & ~(size_t)255;
    int* aux = (int*)((char*)d_ws + off);
    off += 1024;
    int* bcnt = (int*)((char*)d_ws + off);
    off += MAXBKT * 4;
    int* bfill = (int*)((char*)d_ws + off);
    off += MAXBKT * 4;
    float* dinv = (float*)((char*)d_ws + off);
    off += ((size_t)N * 4 + 255) & ~(size_t)255;
    int* csr_src = (int*)((char*)d_ws + off);
    off += ((size_t)E * 4 + 255) & ~(size_t)255;
    int2* ebuf = (int2*)((char*)d_ws + off);
    off += ((size_t)E * 8 + 255) & ~(size_t)255;
    __half* z1 = (__half*)((char*)d_ws + off);
    off += ((size_t)N * ZROW * 2 + 255) & ~(size_t)255;
    __half* z2 = (__half*)((char*)d_ws + off);
    off += ((size_t)N * ZROW * 2 + 255) & ~(size_t)255;
    if (off > ws_size) return;

    const int B = 256;
    int gridN = (N + B - 1) / B;
    int gridE = (int)((E + B - 1) / B);
    int nScanBlocks = (N + SCAN_BLK - 1) / SCAN_BLK;
    // 2 nodes per wave
    long long hopThreads = ((long long)(N + 1) / 2) * 64;
    int gridH = (int)((hopThreads + B - 1) / B);

    // 0. dtype detection
    int n_check = (int)((E < 4096) ? E : 4096);
    detect_dtype_kernel<<<1, 256, 0, stream>>>((const unsigned int*)ei, flag, n_check);

    // 1. CSR build: count(+bucket hist) -> scans -> partition -> bucket fill
    zero2_kernel<<<gridN, B, 0, stream>>>(cnt, N, bcnt, MAXBKT);
    count_bucket_kernel<<<(int)((E + 2047) / 2048), B, 0, stream>>>(ei, cnt, bcnt, flag, E, shift);
    bscan_kernel<<<1, MAXBKT, 0, stream>>>(bcnt, bfill, NBK);
    scanA_kernel<<<nScanBlocks, 256, 0, stream>>>(cnt, row_ptr, aux, N);
    scanB_kernel<<<1, 128, 0, stream>>>(aux, nScanBlocks);
    scanC_kernel<<<gridN, B, 0, stream>>>(row_ptr, aux, cnt, dinv, N, (int)E);
    partition_kernel<<<gridE, B, 0, stream>>>(ei, bfill, ebuf, flag, E, shift);
    bucket_fill_kernel<<<gridE, B, 0, stream>>>(ebuf, row_ptr, cnt, csr_src, E);

    // 2. v0 = D^{-1/2} (x W^T)   [N,64-padded] in fp16
    zgemm_kernel<<<1024, 256, 0, stream>>>(x, W, dinv, z1, N);

    // 3. hops 1,2 in class space (fp16); hop 3 fused with bias+relu+log_softmax
    hop_kernel<<<gridH, B, 0, stream>>>(z1, z2, row_ptr, csr_src, dinv, N);
    hop_kernel<<<gridH, B, 0, stream>>>(z2, z1, row_ptr, csr_src, dinv, N);
    hop_final_kernel<<<gridH, B, 0, stream>>>(z1, b, out, row_ptr, csr_src, dinv, N);
}

// Round 9
// 224.012 us; speedup vs baseline: 3.3056x; 3.3056x over previous
//
#include <hip/hip_runtime.h>
#include <hip/hip_bf16.h>
#include <hip/hip_fp16.h>
#include <stdint.h>

#define NF 64
#define NC 40
#define ZROW 64        // padded z row: 64 halves = 128 B = 2 full cache lines
#define SCAN_BLK 1024  // elements scanned per block (256 threads x 4)

// ---------------------------------------------------------------------------
// Detect whether edge_index was uploaded as int32 or int64.
// ---------------------------------------------------------------------------
__global__ void detect_dtype_kernel(const unsigned int* __restrict__ p, int* __restrict__ flag,
                                    int n_check) {
    __shared__ int s_any;
    if (threadIdx.x == 0) s_any = 0;
    __syncthreads();
    int any = 0;
    for (int i = threadIdx.x; i < n_check; i += blockDim.x) {
        if (p[2 * i + 1] != 0u) any = 1;
    }
    if (any) atomicOr(&s_any, 1);
    __syncthreads();
    if (threadIdx.x == 0) *flag = s_any;
}

__device__ __forceinline__ long long load_idx(const void* p, long long i, int is32) {
    if (is32) return (long long)((const int*)p)[i];
    return ((const long long*)p)[i];
}

__global__ void zero_cnt_kernel(int* __restrict__ cnt, int N) {
    int i = blockIdx.x * blockDim.x + threadIdx.x;
    if (i < N) cnt[i] = 0;
}

// cnt[col[e]] += 1; epos[e] = within-node arrival order (free byproduct of the
// atomic). fill uses it so it needs NO atomics.
__global__ void count_kernel(const void* __restrict__ ei, int* __restrict__ cnt,
                             int* __restrict__ epos, const int* __restrict__ flag, long long E) {
    long long e = (long long)blockIdx.x * blockDim.x + threadIdx.x;
    if (e >= E) return;
    int is32 = *flag;
    int c = (int)load_idx(ei, E + e, is32);
    epos[e] = atomicAdd(&cnt[c], 1);
}

// Per-block exclusive scan of cnt into row_ptr (block-local), block totals -> aux
__global__ void scanA_kernel(const int* __restrict__ cnt, int* __restrict__ row_ptr,
                             int* __restrict__ aux, int N) {
    __shared__ int sd[256];
    int t = threadIdx.x;
    int base = blockIdx.x * SCAN_BLK + t * 4;
    int v[4];
    int s = 0;
#pragma unroll
    for (int j = 0; j < 4; ++j) {
        v[j] = (base + j < N) ? cnt[base + j] : 0;
        s += v[j];
    }
    sd[t] = s;
    __syncthreads();
#pragma unroll
    for (int off = 1; off < 256; off <<= 1) {
        int a = (t >= off) ? sd[t - off] : 0;
        __syncthreads();
        sd[t] += a;
        __syncthreads();
    }
    int run = sd[t] - s;
#pragma unroll
    for (int j = 0; j < 4; ++j) {
        if (base + j < N) row_ptr[base + j] = run;
        run += v[j];
    }
    if (t == 255) aux[blockIdx.x] = sd[255];
}

__global__ void scanB_kernel(int* __restrict__ aux, int nb) {
    __shared__ int sd[128];
    int t = threadIdx.x;
    int v = (t < nb) ? aux[t] : 0;
    sd[t] = v;
    __syncthreads();
#pragma unroll
    for (int off = 1; off < 128; off <<= 1) {
        int a = (t >= off) ? sd[t - off] : 0;
        __syncthreads();
        sd[t] += a;
        __syncthreads();
    }
    if (t < nb) aux[t] = sd[t] - v;
}

// row_ptr[i] += aux[block(i)]; dinv[i] = rsqrt(1+cnt[i])
__global__ void scanC_kernel(int* __restrict__ row_ptr, const int* __restrict__ aux,
                             const int* __restrict__ cnt, float* __restrict__ dinv, int N, int E) {
    int i = blockIdx.x * blockDim.x + threadIdx.x;
    if (i < N) {
        row_ptr[i] += aux[i >> 10];
        dinv[i] = rsqrtf(1.0f + (float)cnt[i]);
    }
    if (i == 0) row_ptr[N] = E;
}

// csr_src[row_ptr[col] + epos[e]] = row   (pure scatter, no atomics)
__global__ void fill_kernel(const void* __restrict__ ei, const int* __restrict__ row_ptr,
                            const int* __restrict__ epos, int* __restrict__ csr_src,
                            const int* __restrict__ flag, long long E) {
    long long e = (long long)blockIdx.x * blockDim.x + threadIdx.x;
    if (e >= E) return;
    int is32 = *flag;
    int r = (int)load_idx(ei, e, is32);
    int c = (int)load_idx(ei, E + e, is32);
    csr_src[row_ptr[c] + epos[e]] = r;
}

// z[i][c] = half( dinv[i] * sum_f x[i][f] * W[c][f] ), rows padded to 64 halves.
// One wave per node; lane c owns class c; W row in VGPRs; x row via wave-uniform
// pointer (scalarizes); coalesced 128B row store. No LDS, no spill.
__global__ __launch_bounds__(256, 2)
void zgemm_kernel(const float* __restrict__ x, const float* __restrict__ W,
                  const float* __restrict__ dinv, __half* __restrict__ z, int N) {
    int lane = threadIdx.x & 63;
    int gwave = (blockIdx.x * blockDim.x + threadIdx.x) >> 6;
    int nwaves = (gridDim.x * blockDim.x) >> 6;

    int c = (lane < NC) ? lane : (NC - 1);
    float wreg[NF];
    const float4* wr = (const float4*)(W + (size_t)c * NF);
#pragma unroll
    for (int i = 0; i < NF / 4; ++i) {
        float4 wv = wr[i];
        wreg[4 * i + 0] = wv.x;
        wreg[4 * i + 1] = wv.y;
        wreg[4 * i + 2] = wv.z;
        wreg[4 * i + 3] = wv.w;
    }

    for (int node = gwave; node < N; node += nwaves) {
        int un = __builtin_amdgcn_readfirstlane(node);
        const float* xr = x + (size_t)un * NF;
        float a0 = 0.f, a1 = 0.f, a2 = 0.f, a3 = 0.f;
#pragma unroll
        for (int k = 0; k < NF; k += 4) {
            a0 += xr[k + 0] * wreg[k + 0];
            a1 += xr[k + 1] * wreg[k + 1];
            a2 += xr[k + 2] * wreg[k + 2];
            a3 += xr[k + 3] * wreg[k + 3];
        }
        float acc = (a0 + a1) + (a2 + a3);
        float di = dinv[un];
        float v = (lane < NC) ? di * acc : 0.0f;
        z[(size_t)un * ZROW + lane] = __float2half(v);
    }
}

// Two nodes per wave; sub = lane&31 holds half2 (classes 2sub, 2sub+1).
// 4-deep load pipeline: 4 independent gathers in flight before first waitcnt.
__device__ __forceinline__ float2 hop_accum(const unsigned int* __restrict__ v32, int sub,
                                            int idx, int beg, int deg, int base,
                                            const int* __restrict__ csr_src, float2 acc) {
    int m = (deg < 32) ? deg : 32;
    int k = 0;
    for (; k + 4 <= m; k += 4) {
        int s0 = __shfl(idx, base + k + 0);
        int s1 = __shfl(idx, base + k + 1);
        int s2 = __shfl(idx, base + k + 2);
        int s3 = __shfl(idx, base + k + 3);
        unsigned int u0 = v32[(size_t)s0 * (ZROW / 2) + sub];
        unsigned int u1 = v32[(size_t)s1 * (ZROW / 2) + sub];
        unsigned int u2 = v32[(size_t)s2 * (ZROW / 2) + sub];
        unsigned int u3 = v32[(size_t)s3 * (ZROW / 2) + sub];
        float2 v0 = __half22float2(*reinterpret_cast<const __half2*>(&u0));
        float2 v1 = __half22float2(*reinterpret_cast<const __half2*>(&u1));
        float2 v2 = __half22float2(*reinterpret_cast<const __half2*>(&u2));
        float2 v3 = __half22float2(*reinterpret_cast<const __half2*>(&u3));
        acc.x += (v0.x + v1.x) + (v2.x + v3.x);
        acc.y += (v0.y + v1.y) + (v2.y + v3.y);
    }
    for (; k < m; ++k) {
        int s = __shfl(idx, base + k);
        unsigned int uu = v32[(size_t)s * (ZROW / 2) + sub];
        float2 v = __half22float2(*reinterpret_cast<const __half2*>(&uu));
        acc.x += v.x;
        acc.y += v.y;
    }
    for (k = 32; k < deg; ++k) {  // rare (Poisson lambda=12.5)
        int s = csr_src[beg + k];
        unsigned int uu = v32[(size_t)s * (ZROW / 2) + sub];
        float2 v = __half22float2(*reinterpret_cast<const __half2*>(&uu));
        acc.x += v.x;
        acc.y += v.y;
    }
    return acc;
}

__global__ void hop_kernel(const __half* __restrict__ vin, __half* __restrict__ vout,
                           const int* __restrict__ row_ptr, const int* __restrict__ csr_src,
                           const float* __restrict__ dinv, int N) {
    int t = blockIdx.x * blockDim.x + threadIdx.x;
    int lane = threadIdx.x & 63;
    int half = lane >> 5;
    int sub = lane & 31;
    int node = ((t >> 6) << 1) + half;
    if (node >= N) return;

    int beg = row_ptr[node];
    int deg = row_ptr[node + 1] - beg;

    const unsigned int* v32 = (const unsigned int*)vin;
    unsigned int u = v32[(size_t)node * (ZROW / 2) + sub];
    float2 acc = __half22float2(*reinterpret_cast<const __half2*>(&u));

    int idx = (sub < deg) ? csr_src[beg + sub] : 0;
    acc = hop_accum(v32, sub, idx, beg, deg, half << 5, csr_src, acc);

    float di = dinv[node];
    float d2 = di * di;
    __half2 o = __float22half2_rn(make_float2(d2 * acc.x, d2 * acc.y));
    ((unsigned int*)vout)[(size_t)node * (ZROW / 2) + sub] = *reinterpret_cast<unsigned int*>(&o);
}

// Final hop fused with bias + relu + log_softmax; reduction within each 32-lane
// half; direct contiguous float2 stores (160B per node).
__global__ void hop_final_kernel(const __half* __restrict__ vin, const float* __restrict__ b,
                                 float* __restrict__ out, const int* __restrict__ row_ptr,
                                 const int* __restrict__ csr_src, const float* __restrict__ dinv,
                                 int N) {
    int t = blockIdx.x * blockDim.x + threadIdx.x;
    int lane = threadIdx.x & 63;
    int half = lane >> 5;
    int sub = lane & 31;
    int node = ((t >> 6) << 1) + half;
    if (node >= N) return;

    int beg = row_ptr[node];
    int deg = row_ptr[node + 1] - beg;

    const unsigned int* v32 = (const unsigned int*)vin;
    unsigned int u = v32[(size_t)node * (ZROW / 2) + sub];
    float2 acc = __half22float2(*reinterpret_cast<const __half2*>(&u));

    int idx = (sub < deg) ? csr_src[beg + sub] : 0;
    acc = hop_accum(v32, sub, idx, beg, deg, half << 5, csr_src, acc);

    float di = dinv[node];
    float2 bv = (sub < NC / 2) ? ((const float2*)b)[sub] : make_float2(0.f, 0.f);
    float lx = fmaxf(di * acc.x + bv.x, 0.0f);  // pad lanes: acc=0,bv=0 -> 0
    float ly = fmaxf(di * acc.y + bv.y, 0.0f);

    float mx = fmaxf(lx, ly);
#pragma unroll
    for (int off = 16; off > 0; off >>= 1) mx = fmaxf(mx, __shfl_xor(mx, off));
    float e = (sub < NC / 2) ? (__expf(lx - mx) + __expf(ly - mx)) : 0.0f;
#pragma unroll
    for (int off = 16; off > 0; off >>= 1) e += __shfl_xor(e, off);
    float lse = mx + __logf(e);

    if (sub < NC / 2)
        ((float2*)out)[(size_t)node * (NC / 2) + sub] = make_float2(lx - lse, ly - lse);
}

extern "C" void kernel_launch(void* const* d_in, const int* in_sizes, int n_in,
                              void* d_out, int out_size, void* d_ws, size_t ws_size,
                              hipStream_t stream) {
    const float* x = (const float*)d_in[0];
    const void* ei = d_in[1];
    const float* W = (const float*)d_in[2];
    const float* b = (const float*)d_in[3];
    float* out = (float*)d_out;

    const int N = in_sizes[0] / NF;          // 100000
    const long long E = in_sizes[1] / 2;     // 1250000

    // workspace layout (256B aligned chunks)
    size_t off = 0;
    int* flag = (int*)((char*)d_ws + off);
    off += 256;
    int* cnt = (int*)((char*)d_ws + off);
    off += ((size_t)N * 4 + 255) & ~(size_t)255;
    int* row_ptr = (int*)((char*)d_ws + off);
    off += ((size_t)(N + 1) * 4 + 255) & ~(size_t)255;
    int* aux = (int*)((char*)d_ws + off);
    off += 1024;
    float* dinv = (float*)((char*)d_ws + off);
    off += ((size_t)N * 4 + 255) & ~(size_t)255;
    int* csr_src = (int*)((char*)d_ws + off);
    off += ((size_t)E * 4 + 255) & ~(size_t)255;
    int* epos = (int*)((char*)d_ws + off);
    off += ((size_t)E * 4 + 255) & ~(size_t)255;
    __half* z1 = (__half*)((char*)d_ws + off);
    off += ((size_t)N * ZROW * 2 + 255) & ~(size_t)255;
    __half* z2 = (__half*)((char*)d_ws + off);
    off += ((size_t)N * ZROW * 2 + 255) & ~(size_t)255;
    if (off > ws_size) return;

    const int B = 256;
    int gridN = (N + B - 1) / B;
    int gridE = (int)((E + B - 1) / B);
    int nScanBlocks = (N + SCAN_BLK - 1) / SCAN_BLK;
    long long hopThreads = ((long long)(N + 1) / 2) * 64;  // 2 nodes per wave
    int gridH = (int)((hopThreads + B - 1) / B);

    // 0. dtype detection
    int n_check = (int)((E < 4096) ? E : 4096);
    detect_dtype_kernel<<<1, 256, 0, stream>>>((const unsigned int*)ei, flag, n_check);

    // 1. CSR build: count(+epos) -> scan -> fill(no atomics) ; dinv from degrees
    zero_cnt_kernel<<<gridN, B, 0, stream>>>(cnt, N);
    count_kernel<<<gridE, B, 0, stream>>>(ei, cnt, epos, flag, E);
    scanA_kernel<<<nScanBlocks, 256, 0, stream>>>(cnt, row_ptr, aux, N);
    scanB_kernel<<<1, 128, 0, stream>>>(aux, nScanBlocks);
    scanC_kernel<<<gridN, B, 0, stream>>>(row_ptr, aux, cnt, dinv, N, (int)E);
    fill_kernel<<<gridE, B, 0, stream>>>(ei, row_ptr, epos, csr_src, flag, E);

    // 2. v0 = D^{-1/2} (x W^T)   [N,64-padded] in fp16
    zgemm_kernel<<<1024, 256, 0, stream>>>(x, W, dinv, z1, N);

    // 3. hops 1,2 in class space (fp16); hop 3 fused with bias+relu+log_softmax
    hop_kernel<<<gridH, B, 0, stream>>>(z1, z2, row_ptr, csr_src, dinv, N);
    hop_kernel<<<gridH, B, 0, stream>>>(z2, z1, row_ptr, csr_src, dinv, N);
    hop_final_kernel<<<gridH, B, 0, stream>>>(z1, b, out, row_ptr, csr_src, dinv, N);
}

// Round 10
// 205.820 us; speedup vs baseline: 3.5978x; 1.0884x over previous
//
#include <hip/hip_runtime.h>
#include <hip/hip_bf16.h>
#include <hip/hip_fp16.h>
#include <stdint.h>

#define NF 64
#define NC 40
#define ZROW 64        // padded z row: 64 halves = 128 B = 2 full cache lines
#define SCAN_BLK 1024  // elements scanned per block (256 threads x 4)

typedef _Float16 f16x8 __attribute__((ext_vector_type(8)));
typedef float f32x4 __attribute__((ext_vector_type(4)));

// ---------------------------------------------------------------------------
// Detect whether edge_index was uploaded as int32 or int64.
// ---------------------------------------------------------------------------
__global__ void detect_dtype_kernel(const unsigned int* __restrict__ p, int* __restrict__ flag,
                                    int n_check) {
    __shared__ int s_any;
    if (threadIdx.x == 0) s_any = 0;
    __syncthreads();
    int any = 0;
    for (int i = threadIdx.x; i < n_check; i += blockDim.x) {
        if (p[2 * i + 1] != 0u) any = 1;
    }
    if (any) atomicOr(&s_any, 1);
    __syncthreads();
    if (threadIdx.x == 0) *flag = s_any;
}

__device__ __forceinline__ long long load_idx(const void* p, long long i, int is32) {
    if (is32) return (long long)((const int*)p)[i];
    return ((const long long*)p)[i];
}

__global__ void zero_cnt_kernel(int* __restrict__ cnt, int N) {
    int i = blockIdx.x * blockDim.x + threadIdx.x;
    if (i < N) cnt[i] = 0;
}

// cnt[col[e]] += 1; epos[e] = within-node arrival order (free byproduct of the
// atomic). fill uses it so it needs NO atomics.
__global__ void count_kernel(const void* __restrict__ ei, int* __restrict__ cnt,
                             int* __restrict__ epos, const int* __restrict__ flag, long long E) {
    long long e = (long long)blockIdx.x * blockDim.x + threadIdx.x;
    if (e >= E) return;
    int is32 = *flag;
    int c = (int)load_idx(ei, E + e, is32);
    epos[e] = atomicAdd(&cnt[c], 1);
}

// Per-block exclusive scan of cnt into row_ptr (block-local), block totals -> aux
__global__ void scanA_kernel(const int* __restrict__ cnt, int* __restrict__ row_ptr,
                             int* __restrict__ aux, int N) {
    __shared__ int sd[256];
    int t = threadIdx.x;
    int base = blockIdx.x * SCAN_BLK + t * 4;
    int v[4];
    int s = 0;
#pragma unroll
    for (int j = 0; j < 4; ++j) {
        v[j] = (base + j < N) ? cnt[base + j] : 0;
        s += v[j];
    }
    sd[t] = s;
    __syncthreads();
#pragma unroll
    for (int off = 1; off < 256; off <<= 1) {
        int a = (t >= off) ? sd[t - off] : 0;
        __syncthreads();
        sd[t] += a;
        __syncthreads();
    }
    int run = sd[t] - s;
#pragma unroll
    for (int j = 0; j < 4; ++j) {
        if (base + j < N) row_ptr[base + j] = run;
        run += v[j];
    }
    if (t == 255) aux[blockIdx.x] = sd[255];
}

__global__ void scanB_kernel(int* __restrict__ aux, int nb) {
    __shared__ int sd[128];
    int t = threadIdx.x;
    int v = (t < nb) ? aux[t] : 0;
    sd[t] = v;
    __syncthreads();
#pragma unroll
    for (int off = 1; off < 128; off <<= 1) {
        int a = (t >= off) ? sd[t - off] : 0;
        __syncthreads();
        sd[t] += a;
        __syncthreads();
    }
    if (t < nb) aux[t] = sd[t] - v;
}

// row_ptr[i] += aux[block(i)]; dinv[i] = rsqrt(1+cnt[i])
__global__ void scanC_kernel(int* __restrict__ row_ptr, const int* __restrict__ aux,
                             const int* __restrict__ cnt, float* __restrict__ dinv, int N, int E) {
    int i = blockIdx.x * blockDim.x + threadIdx.x;
    if (i < N) {
        row_ptr[i] += aux[i >> 10];
        dinv[i] = rsqrtf(1.0f + (float)cnt[i]);
    }
    if (i == 0) row_ptr[N] = E;
}

// csr_src[row_ptr[col] + epos[e]] = row   (pure scatter, no atomics)
__global__ void fill_kernel(const void* __restrict__ ei, const int* __restrict__ row_ptr,
                            const int* __restrict__ epos, int* __restrict__ csr_src,
                            const int* __restrict__ flag, long long E) {
    long long e = (long long)blockIdx.x * blockDim.x + threadIdx.x;
    if (e >= E) return;
    int is32 = *flag;
    int r = (int)load_idx(ei, e, is32);
    int c = (int)load_idx(ei, E + e, is32);
    csr_src[row_ptr[c] + epos[e]] = r;
}

// z = D^{-1/2} (x W^T) via MFMA. One wave = 16 nodes x 48 classes (40 + pad).
// A-frag: x[base+(l&15)][kk*32+(l>>4)*8 + 0..7] as f16x8 (2 float4 loads+cvt).
// B-frag: W^T, col=(l&15), same k map; W row clamped at 39, pad classes never
// stored. C/D mapping (m89-verified): col=lane&15, row=(lane>>4)*4+reg.
__global__ void zgemm_mfma_kernel(const float* __restrict__ x, const float* __restrict__ W,
                                  const float* __restrict__ dinv, __half* __restrict__ z,
                                  int N) {
    int lane = threadIdx.x & 63;
    int wid = (blockIdx.x * blockDim.x + threadIdx.x) >> 6;
    int base = wid * 16;
    if (base >= N) return;

    int lrow = lane & 15;  // A row-in-tile / B class col / D class col
    int lk = lane >> 4;    // k-group (8 consecutive k each)

    // B fragments: 3 class-tiles x 2 k-halves, preloaded once.
    f16x8 bfrag[3][2];
#pragma unroll
    for (int ct = 0; ct < 3; ++ct) {
        int wrow = ct * 16 + lrow;
        if (wrow > NC - 1) wrow = NC - 1;  // clamp pad classes (never stored)
        const float* wp = W + (size_t)wrow * NF;
#pragma unroll
        for (int kk = 0; kk < 2; ++kk) {
            float4 wa = *(const float4*)(wp + kk * 32 + lk * 8);
            float4 wb = *(const float4*)(wp + kk * 32 + lk * 8 + 4);
            f16x8 t;
            t[0] = (_Float16)wa.x; t[1] = (_Float16)wa.y;
            t[2] = (_Float16)wa.z; t[3] = (_Float16)wa.w;
            t[4] = (_Float16)wb.x; t[5] = (_Float16)wb.y;
            t[6] = (_Float16)wb.z; t[7] = (_Float16)wb.w;
            bfrag[ct][kk] = t;
        }
    }

    // A fragments for this 16-node tile.
    int arow = base + lrow;
    if (arow > N - 1) arow = N - 1;  // safe dup if N not multiple of 16
    const float* xp = x + (size_t)arow * NF;
    f16x8 afrag[2];
#pragma unroll
    for (int kk = 0; kk < 2; ++kk) {
        float4 xa = *(const float4*)(xp + kk * 32 + lk * 8);
        float4 xb = *(const float4*)(xp + kk * 32 + lk * 8 + 4);
        f16x8 t;
        t[0] = (_Float16)xa.x; t[1] = (_Float16)xa.y;
        t[2] = (_Float16)xa.z; t[3] = (_Float16)xa.w;
        t[4] = (_Float16)xb.x; t[5] = (_Float16)xb.y;
        t[6] = (_Float16)xb.z; t[7] = (_Float16)xb.w;
        afrag[kk] = t;
    }

    f32x4 acc0 = {0.f, 0.f, 0.f, 0.f};
    f32x4 acc1 = {0.f, 0.f, 0.f, 0.f};
    f32x4 acc2 = {0.f, 0.f, 0.f, 0.f};
    acc0 = __builtin_amdgcn_mfma_f32_16x16x32_f16(afrag[0], bfrag[0][0], acc0, 0, 0, 0);
    acc0 = __builtin_amdgcn_mfma_f32_16x16x32_f16(afrag[1], bfrag[0][1], acc0, 0, 0, 0);
    acc1 = __builtin_amdgcn_mfma_f32_16x16x32_f16(afrag[0], bfrag[1][0], acc1, 0, 0, 0);
    acc1 = __builtin_amdgcn_mfma_f32_16x16x32_f16(afrag[1], bfrag[1][1], acc1, 0, 0, 0);
    acc2 = __builtin_amdgcn_mfma_f32_16x16x32_f16(afrag[0], bfrag[2][0], acc2, 0, 0, 0);
    acc2 = __builtin_amdgcn_mfma_f32_16x16x32_f16(afrag[1], bfrag[2][1], acc2, 0, 0, 0);

    // dinv for this lane's 4 output rows (rows lk*4 .. lk*4+3 of the tile)
    float4 dv = *(const float4*)(dinv + base + lk * 4);

#pragma unroll
    for (int r = 0; r < 4; ++r) {
        int row = base + lk * 4 + r;
        if (row >= N) break;
        float d = (r == 0) ? dv.x : (r == 1) ? dv.y : (r == 2) ? dv.z : dv.w;
        __half* zr = z + (size_t)row * ZROW;
        zr[lrow] = __float2half(d * acc0[r]);           // classes 0..15
        zr[16 + lrow] = __float2half(d * acc1[r]);      // classes 16..31
        if (lrow < 8) zr[32 + lrow] = __float2half(d * acc2[r]);  // 32..39
    }
}

// Two nodes per wave; sub = lane&31 holds half2 (classes 2sub, 2sub+1).
// 4-deep load pipeline: 4 independent gathers in flight before first waitcnt.
__device__ __forceinline__ float2 hop_accum(const unsigned int* __restrict__ v32, int sub,
                                            int idx, int beg, int deg, int base,
                                            const int* __restrict__ csr_src, float2 acc) {
    int m = (deg < 32) ? deg : 32;
    int k = 0;
    for (; k + 4 <= m; k += 4) {
        int s0 = __shfl(idx, base + k + 0);
        int s1 = __shfl(idx, base + k + 1);
        int s2 = __shfl(idx, base + k + 2);
        int s3 = __shfl(idx, base + k + 3);
        unsigned int u0 = v32[(size_t)s0 * (ZROW / 2) + sub];
        unsigned int u1 = v32[(size_t)s1 * (ZROW / 2) + sub];
        unsigned int u2 = v32[(size_t)s2 * (ZROW / 2) + sub];
        unsigned int u3 = v32[(size_t)s3 * (ZROW / 2) + sub];
        float2 v0 = __half22float2(*reinterpret_cast<const __half2*>(&u0));
        float2 v1 = __half22float2(*reinterpret_cast<const __half2*>(&u1));
        float2 v2 = __half22float2(*reinterpret_cast<const __half2*>(&u2));
        float2 v3 = __half22float2(*reinterpret_cast<const __half2*>(&u3));
        acc.x += (v0.x + v1.x) + (v2.x + v3.x);
        acc.y += (v0.y + v1.y) + (v2.y + v3.y);
    }
    for (; k < m; ++k) {
        int s = __shfl(idx, base + k);
        unsigned int uu = v32[(size_t)s * (ZROW / 2) + sub];
        float2 v = __half22float2(*reinterpret_cast<const __half2*>(&uu));
        acc.x += v.x;
        acc.y += v.y;
    }
    for (k = 32; k < deg; ++k) {  // rare (Poisson lambda=12.5)
        int s = csr_src[beg + k];
        unsigned int uu = v32[(size_t)s * (ZROW / 2) + sub];
        float2 v = __half22float2(*reinterpret_cast<const __half2*>(&uu));
        acc.x += v.x;
        acc.y += v.y;
    }
    return acc;
}

__global__ void hop_kernel(const __half* __restrict__ vin, __half* __restrict__ vout,
                           const int* __restrict__ row_ptr, const int* __restrict__ csr_src,
                           const float* __restrict__ dinv, int N) {
    int t = blockIdx.x * blockDim.x + threadIdx.x;
    int lane = threadIdx.x & 63;
    int half = lane >> 5;
    int sub = lane & 31;
    int node = ((t >> 6) << 1) + half;
    if (node >= N) return;

    int beg = row_ptr[node];
    int deg = row_ptr[node + 1] - beg;

    const unsigned int* v32 = (const unsigned int*)vin;
    unsigned int u = v32[(size_t)node * (ZROW / 2) + sub];
    float2 acc = __half22float2(*reinterpret_cast<const __half2*>(&u));

    int idx = (sub < deg) ? csr_src[beg + sub] : 0;
    acc = hop_accum(v32, sub, idx, beg, deg, half << 5, csr_src, acc);

    float di = dinv[node];
    float d2 = di * di;
    __half2 o = __float22half2_rn(make_float2(d2 * acc.x, d2 * acc.y));
    ((unsigned int*)vout)[(size_t)node * (ZROW / 2) + sub] = *reinterpret_cast<unsigned int*>(&o);
}

// Final hop fused with bias + relu + log_softmax; reduction within each 32-lane
// half; direct contiguous float2 stores (160B per node).
__global__ void hop_final_kernel(const __half* __restrict__ vin, const float* __restrict__ b,
                                 float* __restrict__ out, const int* __restrict__ row_ptr,
                                 const int* __restrict__ csr_src, const float* __restrict__ dinv,
                                 int N) {
    int t = blockIdx.x * blockDim.x + threadIdx.x;
    int lane = threadIdx.x & 63;
    int half = lane >> 5;
    int sub = lane & 31;
    int node = ((t >> 6) << 1) + half;
    if (node >= N) return;

    int beg = row_ptr[node];
    int deg = row_ptr[node + 1] - beg;

    const unsigned int* v32 = (const unsigned int*)vin;
    unsigned int u = v32[(size_t)node * (ZROW / 2) + sub];
    float2 acc = __half22float2(*reinterpret_cast<const __half2*>(&u));

    int idx = (sub < deg) ? csr_src[beg + sub] : 0;
    acc = hop_accum(v32, sub, idx, beg, deg, half << 5, csr_src, acc);

    float di = dinv[node];
    float2 bv = (sub < NC / 2) ? ((const float2*)b)[sub] : make_float2(0.f, 0.f);
    float lx = fmaxf(di * acc.x + bv.x, 0.0f);  // pad lanes: acc=0,bv=0 -> 0
    float ly = fmaxf(di * acc.y + bv.y, 0.0f);

    float mx = fmaxf(lx, ly);
#pragma unroll
    for (int off = 16; off > 0; off >>= 1) mx = fmaxf(mx, __shfl_xor(mx, off));
    float e = (sub < NC / 2) ? (__expf(lx - mx) + __expf(ly - mx)) : 0.0f;
#pragma unroll
    for (int off = 16; off > 0; off >>= 1) e += __shfl_xor(e, off);
    float lse = mx + __logf(e);

    if (sub < NC / 2)
        ((float2*)out)[(size_t)node * (NC / 2) + sub] = make_float2(lx - lse, ly - lse);
}

extern "C" void kernel_launch(void* const* d_in, const int* in_sizes, int n_in,
                              void* d_out, int out_size, void* d_ws, size_t ws_size,
                              hipStream_t stream) {
    const float* x = (const float*)d_in[0];
    const void* ei = d_in[1];
    const float* W = (const float*)d_in[2];
    const float* b = (const float*)d_in[3];
    float* out = (float*)d_out;

    const int N = in_sizes[0] / NF;          // 100000
    const long long E = in_sizes[1] / 2;     // 1250000

    // workspace layout (256B aligned chunks)
    size_t off = 0;
    int* flag = (int*)((char*)d_ws + off);
    off += 256;
    int* cnt = (int*)((char*)d_ws + off);
    off += ((size_t)N * 4 + 255) & ~(size_t)255;
    int* row_ptr = (int*)((char*)d_ws + off);
    off += ((size_t)(N + 1) * 4 + 255) & ~(size_t)255;
    int* aux = (int*)((char*)d_ws + off);
    off += 1024;
    float* dinv = (float*)((char*)d_ws + off);
    off += ((size_t)N * 4 + 255) & ~(size_t)255;
    int* csr_src = (int*)((char*)d_ws + off);
    off += ((size_t)E * 4 + 255) & ~(size_t)255;
    int* epos = (int*)((char*)d_ws + off);
    off += ((size_t)E * 4 + 255) & ~(size_t)255;
    __half* z1 = (__half*)((char*)d_ws + off);
    size_t z_bytes = (size_t)N * ZROW * 2;
    off += (z_bytes + 255) & ~(size_t)255;
    __half* z2 = (__half*)((char*)d_ws + off);
    off += (z_bytes + 255) & ~(size_t)255;
    if (off > ws_size) return;

    const int B = 256;
    int gridN = (N + B - 1) / B;
    int gridE = (int)((E + B - 1) / B);
    int nScanBlocks = (N + SCAN_BLK - 1) / SCAN_BLK;
    long long hopThreads = ((long long)(N + 1) / 2) * 64;  // 2 nodes per wave
    int gridH = (int)((hopThreads + B - 1) / B);

    // 0. dtype detection
    int n_check = (int)((E < 4096) ? E : 4096);
    detect_dtype_kernel<<<1, 256, 0, stream>>>((const unsigned int*)ei, flag, n_check);

    // 1. CSR build: count(+epos) -> scan -> fill(no atomics) ; dinv from degrees
    zero_cnt_kernel<<<gridN, B, 0, stream>>>(cnt, N);
    count_kernel<<<gridE, B, 0, stream>>>(ei, cnt, epos, flag, E);
    scanA_kernel<<<nScanBlocks, 256, 0, stream>>>(cnt, row_ptr, aux, N);
    scanB_kernel<<<1, 128, 0, stream>>>(aux, nScanBlocks);
    scanC_kernel<<<gridN, B, 0, stream>>>(row_ptr, aux, cnt, dinv, N, (int)E);
    fill_kernel<<<gridE, B, 0, stream>>>(ei, row_ptr, epos, csr_src, flag, E);

    // 2. v0 = D^{-1/2} (x W^T) [N,64-padded] fp16, via MFMA (16 nodes/wave).
    //    z1 pad columns (40..63) must be zero for the hop pad-lane invariant.
    hipMemsetAsync(z1, 0, z_bytes, stream);
    int nWaves = (N + 15) / 16;
    int gridZ = (nWaves + 3) / 4;  // 4 waves per 256-thread block
    zgemm_mfma_kernel<<<gridZ, 256, 0, stream>>>(x, W, dinv, z1, N);

    // 3. hops 1,2 in class space (fp16); hop 3 fused with bias+relu+log_softmax
    hop_kernel<<<gridH, B, 0, stream>>>(z1, z2, row_ptr, csr_src, dinv, N);
    hop_kernel<<<gridH, B, 0, stream>>>(z2, z1, row_ptr, csr_src, dinv, N);
    hop_final_kernel<<<gridH, B, 0, stream>>>(z1, b, out, row_ptr, csr_src, dinv, N);
}